// Round 1
// baseline (569.678 us; speedup 1.0000x reference)
//
#include <hip/hip_runtime.h>
#include <hip/hip_bf16.h>

typedef __bf16 bf16;
typedef __bf16 bf16x4 __attribute__((ext_vector_type(4)));
typedef __bf16 bf16x8 __attribute__((ext_vector_type(8)));
typedef float floatx4 __attribute__((ext_vector_type(4)));

#define B_SEQ 16
#define NLBL  5000
#define DLAT  1024
#define PDIM  1100
#define NROWS (B_SEQ * NLBL)   // 80000 = 625 * 128 exactly

// ---------------- small kernels ----------------

__global__ void convert_kernel(const float* __restrict__ src, bf16* __restrict__ dst, int n4) {
    int i = blockIdx.x * blockDim.x + threadIdx.x;
    if (i >= n4) return;
    floatx4 v = ((const floatx4*)src)[i];
    bf16x4 o; o.x = (bf16)v.x; o.y = (bf16)v.y; o.z = (bf16)v.z; o.w = (bf16)v.w;
    ((bf16x4*)dst)[i] = o;
}

// compact W1[:, 1024:2048] -> bf16 [1024 x 1024]
__global__ void convert_w1l(const float* __restrict__ W1, bf16* __restrict__ dst) {
    int i = blockIdx.x * blockDim.x + threadIdx.x;   // over 1024*1024/4
    if (i >= (1024 * 1024) / 4) return;
    int o = i >> 8;            // 256 float4 per row
    int c = (i & 255) * 4;
    floatx4 v = *(const floatx4*)(W1 + (size_t)o * 2048 + 1024 + c);
    bf16x4 w; w.x = (bf16)v.x; w.y = (bf16)v.y; w.z = (bf16)v.z; w.w = (bf16)v.w;
    *(bf16x4*)(dst + o * 1024 + c) = w;
}

// P_e[b,d] = sum_p seq[b,p] * Wp[d,p]   (f32 exact, tiny)
__global__ void pe_kernel(const float* __restrict__ seq, const float* __restrict__ Wp,
                          float* __restrict__ Pe) {
    int i = blockIdx.x * blockDim.x + threadIdx.x;
    if (i >= B_SEQ * DLAT) return;
    int b = i >> 10, d = i & 1023;
    const float* s = seq + b * PDIM;
    const float* w = Wp + (size_t)d * PDIM;
    float acc = 0.f;
    for (int p = 0; p < PDIM; p += 4) {
        floatx4 a = *(const floatx4*)(s + p);
        floatx4 ww = *(const floatx4*)(w + p);
        acc += a.x * ww.x + a.y * ww.y + a.z * ww.z + a.w * ww.w;
    }
    Pe[i] = acc;
}

// hpb[b,o] = b1[o] + sum_d Pe[b,d] * W1[o, d]   (W1 row stride 2048, first half)
__global__ void hpb_kernel(const float* __restrict__ Pe, const float* __restrict__ W1,
                           const float* __restrict__ b1, float* __restrict__ hpb) {
    int i = blockIdx.x * blockDim.x + threadIdx.x;
    if (i >= B_SEQ * DLAT) return;
    int b = i >> 10, o = i & 1023;
    const float* p = Pe + b * DLAT;
    const float* w = W1 + (size_t)o * 2048;
    float acc = b1[o];
    for (int d = 0; d < DLAT; d += 4) {
        floatx4 a = *(const floatx4*)(p + d);
        floatx4 ww = *(const floatx4*)(w + d);
        acc += a.x * ww.x + a.y * ww.y + a.z * ww.z + a.w * ww.w;
    }
    hpb[i] = acc;
}

__global__ void init_out(float* __restrict__ out, const float* __restrict__ b3) {
    int i = blockIdx.x * blockDim.x + threadIdx.x;
    if (i < NROWS) out[i] = b3[0];
}

// ---------------- generic bf16 GEMM: C[M x 1024] = A[M x 1024] * Bt[1024 x 1024]^T ----------------
// A row-major [M,K=1024], Bt row-major [N=1024,K=1024]. STORE_BF16: C as bf16 else f32.

template <int STORE_BF16>
__global__ __launch_bounds__(256)
void gemm_bt(const bf16* __restrict__ A, const bf16* __restrict__ Bt,
             void* __restrict__ Cout, int M) {
    __shared__ bf16 As[128 * 72];
    __shared__ bf16 Bs[128 * 72];
    const int t = threadIdx.x;
    const int m0 = blockIdx.x * 128;
    const int n0 = blockIdx.y * 128;
    const int wave = t >> 6, lane = t & 63;
    const int wm = (wave & 1) * 64, wn = (wave >> 1) * 64;
    const int lm = lane & 15, quad = lane >> 4;

    const int sr = t >> 3;          // 0..31
    const int sc = (t & 7) * 8;     // bf16 col (16B granule)

    floatx4 acc[4][4] = {};

    for (int k0 = 0; k0 < 1024; k0 += 64) {
#pragma unroll
        for (int p = 0; p < 4; ++p) {
            int r = sr + p * 32;
            int row = m0 + r; if (row >= M) row = M - 1;
            bf16x8 va = *(const bf16x8*)(A + (size_t)row * 1024 + k0 + sc);
            *(bf16x8*)(As + r * 72 + sc) = va;
            bf16x8 vb = *(const bf16x8*)(Bt + (size_t)(n0 + r) * 1024 + k0 + sc);
            *(bf16x8*)(Bs + r * 72 + sc) = vb;
        }
        __syncthreads();
#pragma unroll
        for (int k = 0; k < 64; k += 32) {
            bf16x8 af[4], bg[4];
#pragma unroll
            for (int mi = 0; mi < 4; ++mi)
                af[mi] = *(const bf16x8*)(As + (wm + mi * 16 + lm) * 72 + k + quad * 8);
#pragma unroll
            for (int ni = 0; ni < 4; ++ni)
                bg[ni] = *(const bf16x8*)(Bs + (wn + ni * 16 + lm) * 72 + k + quad * 8);
#pragma unroll
            for (int mi = 0; mi < 4; ++mi)
#pragma unroll
                for (int ni = 0; ni < 4; ++ni)
                    acc[mi][ni] = __builtin_amdgcn_mfma_f32_16x16x32_bf16(af[mi], bg[ni], acc[mi][ni], 0, 0, 0);
        }
        __syncthreads();
    }

#pragma unroll
    for (int mi = 0; mi < 4; ++mi) {
#pragma unroll
        for (int r = 0; r < 4; ++r) {
            int row = m0 + wm + mi * 16 + quad * 4 + r;
            if (row >= M) continue;
#pragma unroll
            for (int ni = 0; ni < 4; ++ni) {
                int col = n0 + wn + ni * 16 + lm;
                float v = acc[mi][ni][r];
                if (STORE_BF16) ((bf16*)Cout)[(size_t)row * 1024 + col] = (bf16)v;
                else            ((float*)Cout)[(size_t)row * 1024 + col] = v;
            }
        }
    }
}

// ---------------- fused final kernel ----------------
// For row r = b*5000+n: logits[r] += sum_{o in tile} W3[o]*relu(b2[o] + sum_d W2[o,d]*A[r,d])
// A[r,d] = relu(hpb[b,d] + hl[n,d]) built on the fly in bf16.

__global__ __launch_bounds__(256)
void fused_gemm(const float* __restrict__ hl, const float* __restrict__ hpb,
                const bf16* __restrict__ W2b, const float* __restrict__ b2,
                const float* __restrict__ W3, float* __restrict__ out) {
    __shared__ bf16 As[128 * 72];
    __shared__ bf16 Bs[128 * 72];
    const int t = threadIdx.x;
    const int m0 = blockIdx.x * 128;   // 625 row tiles (exact)
    const int n0 = blockIdx.y * 128;   // 8 col tiles
    const int wave = t >> 6, lane = t & 63;
    const int wm = (wave & 1) * 64, wn = (wave >> 1) * 64;
    const int lm = lane & 15, quad = lane >> 4;

    // A staging: 16 threads/row (float4 over 64 cols), 16 rows/pass, 8 passes
    const int ar = t >> 4;
    const int ac = (t & 15) * 4;
    unsigned nn[8], bb[8];
#pragma unroll
    for (int p = 0; p < 8; ++p) {
        unsigned row = m0 + ar + p * 16;
        unsigned b = row / 5000u;
        bb[p] = b;
        nn[p] = row - b * 5000u;
    }
    // B staging: 8 threads/row (16B), 32 rows/pass, 4 passes
    const int sr = t >> 3;
    const int sc = (t & 7) * 8;

    floatx4 acc[4][4] = {};

    for (int k0 = 0; k0 < 1024; k0 += 64) {
#pragma unroll
        for (int p = 0; p < 8; ++p) {
            floatx4 vh = *(const floatx4*)(hl + (size_t)nn[p] * 1024 + k0 + ac);
            floatx4 vp = *(const floatx4*)(hpb + (size_t)bb[p] * 1024 + k0 + ac);
            bf16x4 o;
            o.x = (bf16)fmaxf(vh.x + vp.x, 0.f);
            o.y = (bf16)fmaxf(vh.y + vp.y, 0.f);
            o.z = (bf16)fmaxf(vh.z + vp.z, 0.f);
            o.w = (bf16)fmaxf(vh.w + vp.w, 0.f);
            *(bf16x4*)(As + (ar + p * 16) * 72 + ac) = o;
        }
#pragma unroll
        for (int p = 0; p < 4; ++p) {
            int r = sr + p * 32;
            bf16x8 vb = *(const bf16x8*)(W2b + (size_t)(n0 + r) * 1024 + k0 + sc);
            *(bf16x8*)(Bs + r * 72 + sc) = vb;
        }
        __syncthreads();
#pragma unroll
        for (int k = 0; k < 64; k += 32) {
            bf16x8 af[4], bg[4];
#pragma unroll
            for (int mi = 0; mi < 4; ++mi)
                af[mi] = *(const bf16x8*)(As + (wm + mi * 16 + lm) * 72 + k + quad * 8);
#pragma unroll
            for (int ni = 0; ni < 4; ++ni)
                bg[ni] = *(const bf16x8*)(Bs + (wn + ni * 16 + lm) * 72 + k + quad * 8);
#pragma unroll
            for (int mi = 0; mi < 4; ++mi)
#pragma unroll
                for (int ni = 0; ni < 4; ++ni)
                    acc[mi][ni] = __builtin_amdgcn_mfma_f32_16x16x32_bf16(af[mi], bg[ni], acc[mi][ni], 0, 0, 0);
        }
        __syncthreads();
    }

    // epilogue: relu(+b2) * W3, reduce over 64 cols of this wave, atomicAdd per row
    float w3v[4], b2v[4];
#pragma unroll
    for (int ni = 0; ni < 4; ++ni) {
        int col = n0 + wn + ni * 16 + lm;
        w3v[ni] = W3[col];
        b2v[ni] = b2[col];
    }
#pragma unroll
    for (int mi = 0; mi < 4; ++mi) {
#pragma unroll
        for (int r = 0; r < 4; ++r) {
            float s = 0.f;
#pragma unroll
            for (int ni = 0; ni < 4; ++ni)
                s += fmaxf(acc[mi][ni][r] + b2v[ni], 0.f) * w3v[ni];
            s += __shfl_xor(s, 1, 64);
            s += __shfl_xor(s, 2, 64);
            s += __shfl_xor(s, 4, 64);
            s += __shfl_xor(s, 8, 64);
            if (lm == 0) {
                int row = m0 + wm + mi * 16 + quad * 4 + r;
                atomicAdd(out + row, s);
            }
        }
    }
}

// ---------------- launch ----------------

extern "C" void kernel_launch(void* const* d_in, const int* in_sizes, int n_in,
                              void* d_out, int out_size, void* d_ws, size_t ws_size,
                              hipStream_t stream) {
    const float* seq   = (const float*)d_in[0];   // [16,1100]
    const float* label = (const float*)d_in[1];   // [5000,1024]
    const float* Wp    = (const float*)d_in[2];   // [1024,1100]
    const float* Wl    = (const float*)d_in[3];   // [1024,1024]
    const float* W1    = (const float*)d_in[4];   // [1024,2048]
    const float* b1    = (const float*)d_in[5];   // [1024]
    const float* W2    = (const float*)d_in[6];   // [1024,1024]
    const float* b2    = (const float*)d_in[7];   // [1024]
    const float* W3    = (const float*)d_in[8];   // [1,1024]
    const float* b3    = (const float*)d_in[9];   // [1]
    float* out = (float*)d_out;                   // [16,5000] flat

    size_t off = 0;
    auto alloc = [&](size_t bytes) {
        void* p = (char*)d_ws + off;
        off += (bytes + 255) & ~(size_t)255;
        return p;
    };
    bf16* label_b = (bf16*)alloc((size_t)NLBL * 1024 * 2);
    bf16* Wl_b    = (bf16*)alloc((size_t)1024 * 1024 * 2);
    bf16* W1l_b   = (bf16*)alloc((size_t)1024 * 1024 * 2);
    bf16* W2_b    = (bf16*)alloc((size_t)1024 * 1024 * 2);
    bf16* Le_b    = (bf16*)alloc((size_t)NLBL * 1024 * 2);
    float* hl     = (float*)alloc((size_t)NLBL * 1024 * 4);
    float* Pe     = (float*)alloc((size_t)B_SEQ * 1024 * 4);
    float* hpb    = (float*)alloc((size_t)B_SEQ * 1024 * 4);
    (void)ws_size; (void)n_in; (void)in_sizes; (void)out_size;

    // dtype conversions
    {
        int n4 = (NLBL * 1024) / 4;
        convert_kernel<<<(n4 + 255) / 256, 256, 0, stream>>>(label, label_b, n4);
    }
    {
        int n4 = (1024 * 1024) / 4;
        convert_kernel<<<(n4 + 255) / 256, 256, 0, stream>>>(Wl, Wl_b, n4);
        convert_kernel<<<(n4 + 255) / 256, 256, 0, stream>>>(W2, W2_b, n4);
        convert_w1l<<<(n4 + 255) / 256, 256, 0, stream>>>(W1, W1l_b);
    }

    // protein path (f32 exact, tiny)
    pe_kernel<<<(B_SEQ * 1024 + 255) / 256, 256, 0, stream>>>(seq, Wp, Pe);
    hpb_kernel<<<(B_SEQ * 1024 + 255) / 256, 256, 0, stream>>>(Pe, W1, b1, hpb);

    // label path: L_e = label @ Wl.T (bf16 out), hl = L_e @ W1l.T (f32 out)
    {
        dim3 grid((NLBL + 127) / 128, 8);
        gemm_bt<1><<<grid, 256, 0, stream>>>(label_b, Wl_b, (void*)Le_b, NLBL);
        gemm_bt<0><<<grid, 256, 0, stream>>>(Le_b, W1l_b, (void*)hl, NLBL);
    }

    // output init to b3, then fused layer2 + logits
    init_out<<<(NROWS + 255) / 256, 256, 0, stream>>>(out, b3);
    {
        dim3 grid(NROWS / 128, 8);   // 625 x 8
        fused_gemm<<<grid, 256, 0, stream>>>(hl, hpb, W2_b, b2, W3, out);
    }
}

// Round 2
// 498.216 us; speedup vs baseline: 1.1434x; 1.1434x over previous
//
#include <hip/hip_runtime.h>
#include <hip/hip_bf16.h>
#include <stdint.h>

typedef __bf16 bf16;
typedef __bf16 bf16x4 __attribute__((ext_vector_type(4)));
typedef __bf16 bf16x8 __attribute__((ext_vector_type(8)));
typedef float floatx4 __attribute__((ext_vector_type(4)));

#define B_SEQ 16
#define NLBL  5000
#define DLAT  1024
#define PDIM  1100
#define NROWS (B_SEQ * NLBL)   // 80000 = 625 * 128 exactly

__device__ __forceinline__ void gload_lds16(const bf16* g, bf16* l) {
    __builtin_amdgcn_global_load_lds(
        (const __attribute__((address_space(1))) void*)g,
        (__attribute__((address_space(3))) void*)l, 16, 0, 0);
}

// ---------------- small kernels ----------------

__global__ void convert_kernel(const float* __restrict__ src, bf16* __restrict__ dst, int n4) {
    int i = blockIdx.x * blockDim.x + threadIdx.x;
    if (i >= n4) return;
    floatx4 v = ((const floatx4*)src)[i];
    bf16x4 o; o.x = (bf16)v.x; o.y = (bf16)v.y; o.z = (bf16)v.z; o.w = (bf16)v.w;
    ((bf16x4*)dst)[i] = o;
}

// compact W1[:, 1024:2048] -> bf16 [1024 x 1024]
__global__ void convert_w1l(const float* __restrict__ W1, bf16* __restrict__ dst) {
    int i = blockIdx.x * blockDim.x + threadIdx.x;   // over 1024*1024/4
    if (i >= (1024 * 1024) / 4) return;
    int o = i >> 8;
    int c = (i & 255) * 4;
    floatx4 v = *(const floatx4*)(W1 + (size_t)o * 2048 + 1024 + c);
    bf16x4 w; w.x = (bf16)v.x; w.y = (bf16)v.y; w.z = (bf16)v.z; w.w = (bf16)v.w;
    *(bf16x4*)(dst + o * 1024 + c) = w;
}

// WlT[l][d] = Wl[d][l], f32 -> bf16, 32x32 LDS tile transpose
__global__ void transpose_convert(const float* __restrict__ src, bf16* __restrict__ dst) {
    __shared__ float tile[32][33];
    int bx = blockIdx.x * 32, by = blockIdx.y * 32;
    int tx = threadIdx.x & 31, ty = threadIdx.x >> 5;   // 32 x 8
#pragma unroll
    for (int i = 0; i < 32; i += 8)
        tile[ty + i][tx] = src[(size_t)(by + ty + i) * 1024 + bx + tx];
    __syncthreads();
#pragma unroll
    for (int i = 0; i < 32; i += 8)
        dst[(size_t)(bx + ty + i) * 1024 + by + tx] = (bf16)tile[tx][ty + i];
}

// P_e[b,d] = sum_p seq[b,p] * Wp[d,p]   (f32 exact, tiny)
__global__ void pe_kernel(const float* __restrict__ seq, const float* __restrict__ Wp,
                          float* __restrict__ Pe) {
    int i = blockIdx.x * blockDim.x + threadIdx.x;
    if (i >= B_SEQ * DLAT) return;
    int b = i >> 10, d = i & 1023;
    const float* s = seq + b * PDIM;
    const float* w = Wp + (size_t)d * PDIM;
    float acc = 0.f;
    for (int p = 0; p < PDIM; p += 4) {
        floatx4 a = *(const floatx4*)(s + p);
        floatx4 ww = *(const floatx4*)(w + p);
        acc += a.x * ww.x + a.y * ww.y + a.z * ww.z + a.w * ww.w;
    }
    Pe[i] = acc;
}

// hpb[b,o] = b1[o] + sum_d Pe[b,d] * W1[o, d]   (f32 exact; b1 folded here)
__global__ void hpb_kernel(const float* __restrict__ Pe, const float* __restrict__ W1,
                           const float* __restrict__ b1, float* __restrict__ hpb) {
    int i = blockIdx.x * blockDim.x + threadIdx.x;
    if (i >= B_SEQ * DLAT) return;
    int b = i >> 10, o = i & 1023;
    const float* p = Pe + b * DLAT;
    const float* w = W1 + (size_t)o * 2048;
    float acc = b1[o];
    for (int d = 0; d < DLAT; d += 4) {
        floatx4 a = *(const floatx4*)(p + d);
        floatx4 ww = *(const floatx4*)(w + d);
        acc += a.x * ww.x + a.y * ww.y + a.z * ww.z + a.w * ww.w;
    }
    hpb[i] = acc;
}

__global__ void init_out(float* __restrict__ out, const float* __restrict__ b3) {
    int i = blockIdx.x * blockDim.x + threadIdx.x;
    if (i < NROWS) out[i] = b3[0];
}

// h1[lrow, d] = bf16(relu(hpb[b,d] + hl[n,d])), row = row_base + lrow, b=row/5000, n=row%5000
__global__ void build_h1(const float* __restrict__ hl, const float* __restrict__ hpb,
                         bf16* __restrict__ h1, int row_base) {
    int lrow = blockIdx.x * 2 + (threadIdx.x >> 7);
    int row = row_base + lrow;
    int c = (threadIdx.x & 127) * 8;
    unsigned b = (unsigned)row / 5000u;
    unsigned n = (unsigned)row - b * 5000u;
    const float* ph = hl + (size_t)n * 1024 + c;
    const float* pp = hpb + b * 1024 + c;
    floatx4 h0 = *(const floatx4*)ph;
    floatx4 h4 = *(const floatx4*)(ph + 4);
    floatx4 p0 = *(const floatx4*)pp;
    floatx4 p4 = *(const floatx4*)(pp + 4);
    bf16x8 o;
    o[0] = (bf16)fmaxf(h0.x + p0.x, 0.f); o[1] = (bf16)fmaxf(h0.y + p0.y, 0.f);
    o[2] = (bf16)fmaxf(h0.z + p0.z, 0.f); o[3] = (bf16)fmaxf(h0.w + p0.w, 0.f);
    o[4] = (bf16)fmaxf(h4.x + p4.x, 0.f); o[5] = (bf16)fmaxf(h4.y + p4.y, 0.f);
    o[6] = (bf16)fmaxf(h4.z + p4.z, 0.f); o[7] = (bf16)fmaxf(h4.w + p4.w, 0.f);
    *(bf16x8*)(h1 + (size_t)lrow * 1024 + c) = o;
}

// ---------------- m97-style GEMM with global_load_lds + XOR-swizzled LDS ----------------
// C[m,n] = sum_k A[m,k] * Bt[n,k];  K=1024, N=1024, tiles 128x128x64.
// LDS layout: LDS[row][j] (16B granules, j=0..7) holds global granule j^(row&7).

template <int STORE_BF16>
__global__ __launch_bounds__(256)
void gemm_bt_glds(const bf16* __restrict__ A, const bf16* __restrict__ Bt,
                  void* __restrict__ Cout, int M) {
    __shared__ bf16 As[128 * 64];
    __shared__ bf16 Bs[128 * 64];
    const int t = threadIdx.x;
    const int n0 = blockIdx.x * 128;
    const int m0 = blockIdx.y * 128;
    const int wave = t >> 6, lane = t & 63;
    const int wm = (wave & 1) * 64, wn = (wave >> 1) * 64;
    const int lm = lane & 15, quad = lane >> 4;
    const int sw = lm & 7;

    const int srow = t >> 3;            // 0..31
    const int scg0 = t & 7;
    const int sbase = (t & 192) * 8;    // wave-uniform LDS base (elements), + p*2048

    floatx4 acc[4][4] = {};

    for (int k0 = 0; k0 < 1024; k0 += 64) {
#pragma unroll
        for (int p = 0; p < 4; ++p) {
            int row = p * 32 + srow;
            int cg = scg0 ^ (row & 7);
            int grow = m0 + row; if (grow >= M) grow = M - 1;
            gload_lds16(A + (size_t)grow * 1024 + k0 + cg * 8, As + p * 2048 + sbase);
        }
#pragma unroll
        for (int p = 0; p < 4; ++p) {
            int row = p * 32 + srow;
            int cg = scg0 ^ (row & 7);
            gload_lds16(Bt + (size_t)(n0 + row) * 1024 + k0 + cg * 8, Bs + p * 2048 + sbase);
        }
        __syncthreads();
#pragma unroll
        for (int k = 0; k < 64; k += 32) {
            bf16x8 af[4], bg[4];
            int ko = (((k >> 3) + quad) ^ sw) * 8;
#pragma unroll
            for (int mi = 0; mi < 4; ++mi)
                af[mi] = *(const bf16x8*)(As + (wm + mi * 16 + lm) * 64 + ko);
#pragma unroll
            for (int ni = 0; ni < 4; ++ni)
                bg[ni] = *(const bf16x8*)(Bs + (wn + ni * 16 + lm) * 64 + ko);
#pragma unroll
            for (int mi = 0; mi < 4; ++mi)
#pragma unroll
                for (int ni = 0; ni < 4; ++ni)
                    acc[mi][ni] = __builtin_amdgcn_mfma_f32_16x16x32_bf16(af[mi], bg[ni], acc[mi][ni], 0, 0, 0);
        }
        __syncthreads();
    }

#pragma unroll
    for (int mi = 0; mi < 4; ++mi) {
#pragma unroll
        for (int r = 0; r < 4; ++r) {
            int row = m0 + wm + mi * 16 + quad * 4 + r;
            if (row >= M) continue;
#pragma unroll
            for (int ni = 0; ni < 4; ++ni) {
                int col = n0 + wn + ni * 16 + lm;
                float v = acc[mi][ni][r];
                if (STORE_BF16) ((bf16*)Cout)[(size_t)row * 1024 + col] = (bf16)v;
                else            ((float*)Cout)[(size_t)row * 1024 + col] = v;
            }
        }
    }
}

// ---------------- main fused GEMM: C = h1 @ W2.T, epilogue relu(+b2)*W3 -> atomicAdd out ----------------

__global__ __launch_bounds__(256)
void gemm_h2(const bf16* __restrict__ h1, const bf16* __restrict__ W2b,
             const float* __restrict__ b2, const float* __restrict__ W3,
             float* __restrict__ out, int row_base) {
    __shared__ bf16 As[128 * 64];
    __shared__ bf16 Bs[128 * 64];
    const int t = threadIdx.x;
    const int n0 = blockIdx.x * 128;    // 8 col tiles
    const int m0 = blockIdx.y * 128;    // local row tile within chunk
    const int wave = t >> 6, lane = t & 63;
    const int wm = (wave & 1) * 64, wn = (wave >> 1) * 64;
    const int lm = lane & 15, quad = lane >> 4;
    const int sw = lm & 7;

    const int srow = t >> 3;
    const int scg0 = t & 7;
    const int sbase = (t & 192) * 8;

    floatx4 acc[4][4] = {};
    const bf16* Abase = h1 + (size_t)m0 * 1024;
    const bf16* Bbase = W2b + (size_t)n0 * 1024;

    for (int k0 = 0; k0 < 1024; k0 += 64) {
#pragma unroll
        for (int p = 0; p < 4; ++p) {
            int row = p * 32 + srow;
            int cg = scg0 ^ (row & 7);
            gload_lds16(Abase + (size_t)row * 1024 + k0 + cg * 8, As + p * 2048 + sbase);
        }
#pragma unroll
        for (int p = 0; p < 4; ++p) {
            int row = p * 32 + srow;
            int cg = scg0 ^ (row & 7);
            gload_lds16(Bbase + (size_t)row * 1024 + k0 + cg * 8, Bs + p * 2048 + sbase);
        }
        __syncthreads();
#pragma unroll
        for (int k = 0; k < 64; k += 32) {
            bf16x8 af[4], bg[4];
            int ko = (((k >> 3) + quad) ^ sw) * 8;
#pragma unroll
            for (int mi = 0; mi < 4; ++mi)
                af[mi] = *(const bf16x8*)(As + (wm + mi * 16 + lm) * 64 + ko);
#pragma unroll
            for (int ni = 0; ni < 4; ++ni)
                bg[ni] = *(const bf16x8*)(Bs + (wn + ni * 16 + lm) * 64 + ko);
#pragma unroll
            for (int mi = 0; mi < 4; ++mi)
#pragma unroll
                for (int ni = 0; ni < 4; ++ni)
                    acc[mi][ni] = __builtin_amdgcn_mfma_f32_16x16x32_bf16(af[mi], bg[ni], acc[mi][ni], 0, 0, 0);
        }
        __syncthreads();
    }

    float w3v[4], b2v[4];
#pragma unroll
    for (int ni = 0; ni < 4; ++ni) {
        int col = n0 + wn + ni * 16 + lm;
        w3v[ni] = W3[col];
        b2v[ni] = b2[col];
    }
#pragma unroll
    for (int mi = 0; mi < 4; ++mi) {
#pragma unroll
        for (int r = 0; r < 4; ++r) {
            float s = 0.f;
#pragma unroll
            for (int ni = 0; ni < 4; ++ni)
                s += fmaxf(acc[mi][ni][r] + b2v[ni], 0.f) * w3v[ni];
            s += __shfl_xor(s, 1, 64);
            s += __shfl_xor(s, 2, 64);
            s += __shfl_xor(s, 4, 64);
            s += __shfl_xor(s, 8, 64);
            if (lm == 0)
                atomicAdd(out + row_base + m0 + wm + mi * 16 + quad * 4 + r, s);
        }
    }
}

// ---------------- launch ----------------

extern "C" void kernel_launch(void* const* d_in, const int* in_sizes, int n_in,
                              void* d_out, int out_size, void* d_ws, size_t ws_size,
                              hipStream_t stream) {
    const float* seq   = (const float*)d_in[0];
    const float* label = (const float*)d_in[1];
    const float* Wp    = (const float*)d_in[2];
    const float* Wl    = (const float*)d_in[3];
    const float* W1    = (const float*)d_in[4];
    const float* b1    = (const float*)d_in[5];
    const float* W2    = (const float*)d_in[6];
    const float* b2    = (const float*)d_in[7];
    const float* W3    = (const float*)d_in[8];
    const float* b3    = (const float*)d_in[9];
    float* out = (float*)d_out;
    (void)n_in; (void)in_sizes; (void)out_size;

    size_t off = 0;
    auto alloc = [&](size_t bytes) {
        void* p = (char*)d_ws + off;
        off += (bytes + 255) & ~(size_t)255;
        return p;
    };
    bf16* label_b = (bf16*)alloc((size_t)NLBL * 1024 * 2);
    bf16* WlT_b   = (bf16*)alloc((size_t)1024 * 1024 * 2);
    bf16* W1l_b   = (bf16*)alloc((size_t)1024 * 1024 * 2);
    bf16* W2_b    = (bf16*)alloc((size_t)1024 * 1024 * 2);
    bf16* M_bf    = (bf16*)alloc((size_t)1024 * 1024 * 2);
    float* hl     = (float*)alloc((size_t)NLBL * 1024 * 4);
    float* Pe     = (float*)alloc((size_t)B_SEQ * 1024 * 4);
    float* hpb    = (float*)alloc((size_t)B_SEQ * 1024 * 4);
    bf16* h1      = (bf16*)((char*)d_ws + off);

    // chunk the h1 materialization to whatever ws is left (multiple of 128 rows)
    size_t remain = (ws_size > off) ? (ws_size - off) : 0;
    long max_rows = (long)(remain / (1024 * 2));
    int chunk = (int)((max_rows / 128) * 128);
    if (chunk > NROWS) chunk = NROWS;
    if (chunk < 128) chunk = 128;

    // dtype conversions
    {
        int n4 = (NLBL * 1024) / 4;
        convert_kernel<<<(n4 + 255) / 256, 256, 0, stream>>>(label, label_b, n4);
    }
    {
        int n4 = (1024 * 1024) / 4;
        convert_kernel<<<(n4 + 255) / 256, 256, 0, stream>>>(W2, W2_b, n4);
        convert_w1l<<<(n4 + 255) / 256, 256, 0, stream>>>(W1, W1l_b);
        transpose_convert<<<dim3(32, 32), 256, 0, stream>>>(Wl, WlT_b);
    }

    // protein path (f32 exact)
    pe_kernel<<<(B_SEQ * 1024 + 255) / 256, 256, 0, stream>>>(seq, Wp, Pe);
    hpb_kernel<<<(B_SEQ * 1024 + 255) / 256, 256, 0, stream>>>(Pe, W1, b1, hpb);

    // label path: Mmat = W1l @ Wl  (tiny), then hl = label @ Mmat.T
    gemm_bt_glds<1><<<dim3(8, 8), 256, 0, stream>>>(W1l_b, WlT_b, (void*)M_bf, 1024);
    gemm_bt_glds<0><<<dim3(8, (NLBL + 127) / 128), 256, 0, stream>>>(label_b, M_bf, (void*)hl, NLBL);

    // out = b3, then chunked: h1 = relu(hpb+hl), out += relu(h1@W2.T + b2) @ W3
    init_out<<<(NROWS + 255) / 256, 256, 0, stream>>>(out, b3);
    for (int rb = 0; rb < NROWS; rb += chunk) {
        int rows = (NROWS - rb) < chunk ? (NROWS - rb) : chunk;
        build_h1<<<rows / 2, 256, 0, stream>>>(hl, hpb, h1, rb);
        gemm_h2<<<dim3(8, rows / 128), 256, 0, stream>>>(h1, W2_b, b2, W3, out, rb);
    }
}

// Round 3
// 417.290 us; speedup vs baseline: 1.3652x; 1.1939x over previous
//
#include <hip/hip_runtime.h>
#include <hip/hip_bf16.h>
#include <stdint.h>

typedef __bf16 bf16;
typedef __bf16 bf16x4 __attribute__((ext_vector_type(4)));
typedef __bf16 bf16x8 __attribute__((ext_vector_type(8)));
typedef float floatx4 __attribute__((ext_vector_type(4)));

#define B_SEQ 16
#define NLBL  5000
#define DLAT  1024
#define PDIM  1100
#define NROWS (B_SEQ * NLBL)   // 80000 = 625 * 128 exactly

__device__ __forceinline__ void gload_lds16(const bf16* g, bf16* l) {
    __builtin_amdgcn_global_load_lds(
        (const __attribute__((address_space(1))) void*)g,
        (__attribute__((address_space(3))) void*)l, 16, 0, 0);
}

// ---------------- small kernels ----------------

__global__ void convert_kernel(const float* __restrict__ src, bf16* __restrict__ dst, int n4) {
    int i = blockIdx.x * blockDim.x + threadIdx.x;
    if (i >= n4) return;
    floatx4 v = ((const floatx4*)src)[i];
    bf16x4 o; o.x = (bf16)v.x; o.y = (bf16)v.y; o.z = (bf16)v.z; o.w = (bf16)v.w;
    ((bf16x4*)dst)[i] = o;
}

// compact W1[:, 1024:2048] -> bf16 [1024 x 1024]
__global__ void convert_w1l(const float* __restrict__ W1, bf16* __restrict__ dst) {
    int i = blockIdx.x * blockDim.x + threadIdx.x;
    if (i >= (1024 * 1024) / 4) return;
    int o = i >> 8;
    int c = (i & 255) * 4;
    floatx4 v = *(const floatx4*)(W1 + (size_t)o * 2048 + 1024 + c);
    bf16x4 w; w.x = (bf16)v.x; w.y = (bf16)v.y; w.z = (bf16)v.z; w.w = (bf16)v.w;
    *(bf16x4*)(dst + o * 1024 + c) = w;
}

// WlT[l][d] = Wl[d][l], f32 -> bf16
__global__ void transpose_convert(const float* __restrict__ src, bf16* __restrict__ dst) {
    __shared__ float tile[32][33];
    int bx = blockIdx.x * 32, by = blockIdx.y * 32;
    int tx = threadIdx.x & 31, ty = threadIdx.x >> 5;
#pragma unroll
    for (int i = 0; i < 32; i += 8)
        tile[ty + i][tx] = src[(size_t)(by + ty + i) * 1024 + bx + tx];
    __syncthreads();
#pragma unroll
    for (int i = 0; i < 32; i += 8)
        dst[(size_t)(bx + ty + i) * 1024 + by + tx] = (bf16)tile[tx][ty + i];
}

// Pe[b,d] = seq[b,:] . Wp[d,:]  — one wave per d, lanes along K, coalesced.
__global__ void pe_kernel(const float* __restrict__ seq, const float* __restrict__ Wp,
                          float* __restrict__ Pe) {
    int w = (blockIdx.x * blockDim.x + threadIdx.x) >> 6;   // d = 0..1023
    int l = threadIdx.x & 63;
    if (w >= DLAT) return;
    floatx4 wv[5];
#pragma unroll
    for (int k = 0; k < 5; ++k) {
        int g = l + 64 * k;                                  // granule, 275 valid
        wv[k] = (g < 275) ? *(const floatx4*)(Wp + (size_t)w * PDIM + g * 4)
                          : floatx4{0.f, 0.f, 0.f, 0.f};
    }
    for (int b = 0; b < B_SEQ; ++b) {
        float acc = 0.f;
#pragma unroll
        for (int k = 0; k < 5; ++k) {
            int g = l + 64 * k;
            if (g < 275) {
                floatx4 sv = *(const floatx4*)(seq + (size_t)b * PDIM + g * 4);
                acc += wv[k].x * sv.x + wv[k].y * sv.y + wv[k].z * sv.z + wv[k].w * sv.w;
            }
        }
#pragma unroll
        for (int off = 32; off; off >>= 1) acc += __shfl_xor(acc, off, 64);
        if (l == 0) Pe[b * DLAT + w] = acc;
    }
}

// hpb[b,o] = b1[o] + Pe[b,:] . W1[o, 0:1024]  — one wave per o, coalesced.
__global__ void hpb_kernel(const float* __restrict__ Pe, const float* __restrict__ W1,
                           const float* __restrict__ b1, float* __restrict__ hpb) {
    int w = (blockIdx.x * blockDim.x + threadIdx.x) >> 6;   // o = 0..1023
    int l = threadIdx.x & 63;
    if (w >= DLAT) return;
    floatx4 wv[4];
#pragma unroll
    for (int k = 0; k < 4; ++k)
        wv[k] = *(const floatx4*)(W1 + (size_t)w * 2048 + (l + 64 * k) * 4);
    for (int b = 0; b < B_SEQ; ++b) {
        float acc = 0.f;
#pragma unroll
        for (int k = 0; k < 4; ++k) {
            floatx4 pv = *(const floatx4*)(Pe + (size_t)b * DLAT + (l + 64 * k) * 4);
            acc += wv[k].x * pv.x + wv[k].y * pv.y + wv[k].z * pv.z + wv[k].w * pv.w;
        }
#pragma unroll
        for (int off = 32; off; off >>= 1) acc += __shfl_xor(acc, off, 64);
        if (l == 0) hpb[b * DLAT + w] = acc + b1[w];
    }
}

__global__ void init_out(float* __restrict__ out, const float* __restrict__ b3) {
    int i = blockIdx.x * blockDim.x + threadIdx.x;
    if (i < NROWS) out[i] = b3[0];
}

// h1[lrow, d] = bf16(relu(hpb[b,d] + hl[n,d]))
__global__ void build_h1(const float* __restrict__ hl, const float* __restrict__ hpb,
                         bf16* __restrict__ h1, int row_base) {
    int lrow = blockIdx.x * 2 + (threadIdx.x >> 7);
    int row = row_base + lrow;
    int c = (threadIdx.x & 127) * 8;
    unsigned b = (unsigned)row / 5000u;
    unsigned n = (unsigned)row - b * 5000u;
    const float* ph = hl + (size_t)n * 1024 + c;
    const float* pp = hpb + b * 1024 + c;
    floatx4 h0 = *(const floatx4*)ph;
    floatx4 h4 = *(const floatx4*)(ph + 4);
    floatx4 p0 = *(const floatx4*)pp;
    floatx4 p4 = *(const floatx4*)(pp + 4);
    bf16x8 o;
    o[0] = (bf16)fmaxf(h0.x + p0.x, 0.f); o[1] = (bf16)fmaxf(h0.y + p0.y, 0.f);
    o[2] = (bf16)fmaxf(h0.z + p0.z, 0.f); o[3] = (bf16)fmaxf(h0.w + p0.w, 0.f);
    o[4] = (bf16)fmaxf(h4.x + p4.x, 0.f); o[5] = (bf16)fmaxf(h4.y + p4.y, 0.f);
    o[6] = (bf16)fmaxf(h4.z + p4.z, 0.f); o[7] = (bf16)fmaxf(h4.w + p4.w, 0.f);
    *(bf16x8*)(h1 + (size_t)lrow * 1024 + c) = o;
}

// ---------------- 128x128 GEMM w/ glds + XOR swizzle (used for hl) ----------------

template <int STORE_BF16>
__global__ __launch_bounds__(256)
void gemm_bt_glds(const bf16* __restrict__ A, const bf16* __restrict__ Bt,
                  void* __restrict__ Cout, int M) {
    __shared__ bf16 As[128 * 64];
    __shared__ bf16 Bs[128 * 64];
    const int t = threadIdx.x;
    const int n0 = blockIdx.x * 128;
    const int m0 = blockIdx.y * 128;
    const int wave = t >> 6, lane = t & 63;
    const int wm = (wave & 1) * 64, wn = (wave >> 1) * 64;
    const int lm = lane & 15, quad = lane >> 4;
    const int sw = lm & 7;
    const int srow = t >> 3;
    const int scg0 = t & 7;
    const int sbase = (t & 192) * 8;

    floatx4 acc[4][4] = {};

    for (int k0 = 0; k0 < 1024; k0 += 64) {
#pragma unroll
        for (int p = 0; p < 4; ++p) {
            int row = p * 32 + srow;
            int cg = scg0 ^ (row & 7);
            int grow = m0 + row; if (grow >= M) grow = M - 1;
            gload_lds16(A + (size_t)grow * 1024 + k0 + cg * 8, As + p * 2048 + sbase);
        }
#pragma unroll
        for (int p = 0; p < 4; ++p) {
            int row = p * 32 + srow;
            int cg = scg0 ^ (row & 7);
            gload_lds16(Bt + (size_t)(n0 + row) * 1024 + k0 + cg * 8, Bs + p * 2048 + sbase);
        }
        __syncthreads();
#pragma unroll
        for (int k = 0; k < 64; k += 32) {
            bf16x8 af[4], bg[4];
            int ko = (((k >> 3) + quad) ^ sw) * 8;
#pragma unroll
            for (int mi = 0; mi < 4; ++mi)
                af[mi] = *(const bf16x8*)(As + (wm + mi * 16 + lm) * 64 + ko);
#pragma unroll
            for (int ni = 0; ni < 4; ++ni)
                bg[ni] = *(const bf16x8*)(Bs + (wn + ni * 16 + lm) * 64 + ko);
#pragma unroll
            for (int mi = 0; mi < 4; ++mi)
#pragma unroll
                for (int ni = 0; ni < 4; ++ni)
                    acc[mi][ni] = __builtin_amdgcn_mfma_f32_16x16x32_bf16(af[mi], bg[ni], acc[mi][ni], 0, 0, 0);
        }
        __syncthreads();
    }

#pragma unroll
    for (int mi = 0; mi < 4; ++mi) {
#pragma unroll
        for (int r = 0; r < 4; ++r) {
            int row = m0 + wm + mi * 16 + quad * 4 + r;
            if (row >= M) continue;
#pragma unroll
            for (int ni = 0; ni < 4; ++ni) {
                int col = n0 + wn + ni * 16 + lm;
                float v = acc[mi][ni][r];
                if (STORE_BF16) ((bf16*)Cout)[(size_t)row * 1024 + col] = (bf16)v;
                else            ((float*)Cout)[(size_t)row * 1024 + col] = v;
            }
        }
    }
}

// ---------------- 64x64-tile GEMM for the 1024^3 M-product (256 blocks) ----------------

__global__ __launch_bounds__(256)
void gemm64_bt(const bf16* __restrict__ A, const bf16* __restrict__ Bt,
               bf16* __restrict__ C) {
    __shared__ bf16 As[64 * 64];
    __shared__ bf16 Bs[64 * 64];
    const int t = threadIdx.x;
    const int n0 = blockIdx.x * 64;
    const int m0 = blockIdx.y * 64;
    const int wave = t >> 6, lane = t & 63;
    const int wm = (wave & 1) * 32, wn = (wave >> 1) * 32;
    const int lm = lane & 15, quad = lane >> 4;
    const int srow = t >> 2;            // 0..63
    const int sq = t & 3;

    floatx4 acc[2][2] = {};

    for (int k0 = 0; k0 < 1024; k0 += 64) {
#pragma unroll
        for (int p = 0; p < 2; ++p) {
            int cg = (p * 4 + sq) ^ (srow & 7);
            gload_lds16(A + (size_t)(m0 + srow) * 1024 + k0 + cg * 8, As + p * 2048 + (t & 192) * 8);
            gload_lds16(Bt + (size_t)(n0 + srow) * 1024 + k0 + cg * 8, Bs + p * 2048 + (t & 192) * 8);
        }
        __syncthreads();
#pragma unroll
        for (int ks = 0; ks < 2; ++ks) {
            bf16x8 af[2], bg[2];
#pragma unroll
            for (int mi = 0; mi < 2; ++mi) {
                int r = wm + mi * 16 + lm;
                int cg = (ks * 4 + quad) ^ (r & 7);
                af[mi] = *(const bf16x8*)(As + (cg >> 2) * 2048 + r * 32 + (cg & 3) * 8);
            }
#pragma unroll
            for (int ni = 0; ni < 2; ++ni) {
                int r = wn + ni * 16 + lm;
                int cg = (ks * 4 + quad) ^ (r & 7);
                bg[ni] = *(const bf16x8*)(Bs + (cg >> 2) * 2048 + r * 32 + (cg & 3) * 8);
            }
#pragma unroll
            for (int mi = 0; mi < 2; ++mi)
#pragma unroll
                for (int ni = 0; ni < 2; ++ni)
                    acc[mi][ni] = __builtin_amdgcn_mfma_f32_16x16x32_bf16(af[mi], bg[ni], acc[mi][ni], 0, 0, 0);
        }
        __syncthreads();
    }

#pragma unroll
    for (int mi = 0; mi < 2; ++mi)
#pragma unroll
        for (int r = 0; r < 4; ++r)
#pragma unroll
            for (int ni = 0; ni < 2; ++ni) {
                int row = m0 + wm + mi * 16 + quad * 4 + r;
                int col = n0 + wn + ni * 16 + lm;
                C[(size_t)row * 1024 + col] = (bf16)acc[mi][ni][r];
            }
}

// ---------------- main fused GEMM ----------------
// FLAT=1: grid 5000 1-D, XCD-affinity mapping (block->XCD = id%8; each XCD owns
// 78 contiguous m-tiles, n fastest) so an h1 row-tile is fetched into ONE XCD L2.

template <int FLAT>
__global__ __launch_bounds__(256)
void gemm_h2(const bf16* __restrict__ h1, const bf16* __restrict__ W2b,
             const float* __restrict__ b2, const float* __restrict__ W3,
             float* __restrict__ out, int row_base) {
    __shared__ bf16 As[128 * 64];
    __shared__ bf16 Bs[128 * 64];
    const int t = threadIdx.x;
    int m0, n0;
    if (FLAT) {
        int flat = blockIdx.x;
        int x = flat & 7;
        int s = flat >> 3;                 // 0..624
        int mt, nt;
        if (s < 624) { mt = x * 78 + (s >> 3); nt = s & 7; }
        else         { mt = 624; nt = x; }
        m0 = mt * 128; n0 = nt * 128;
    } else {
        n0 = blockIdx.x * 128;
        m0 = blockIdx.y * 128;
    }
    const int wave = t >> 6, lane = t & 63;
    const int wm = (wave & 1) * 64, wn = (wave >> 1) * 64;
    const int lm = lane & 15, quad = lane >> 4;
    const int sw = lm & 7;
    const int srow = t >> 3;
    const int scg0 = t & 7;
    const int sbase = (t & 192) * 8;

    floatx4 acc[4][4] = {};
    const bf16* Abase = h1 + (size_t)m0 * 1024;
    const bf16* Bbase = W2b + (size_t)n0 * 1024;

    for (int k0 = 0; k0 < 1024; k0 += 64) {
#pragma unroll
        for (int p = 0; p < 4; ++p) {
            int row = p * 32 + srow;
            int cg = scg0 ^ (row & 7);
            gload_lds16(Abase + (size_t)row * 1024 + k0 + cg * 8, As + p * 2048 + sbase);
        }
#pragma unroll
        for (int p = 0; p < 4; ++p) {
            int row = p * 32 + srow;
            int cg = scg0 ^ (row & 7);
            gload_lds16(Bbase + (size_t)row * 1024 + k0 + cg * 8, Bs + p * 2048 + sbase);
        }
        __syncthreads();
#pragma unroll
        for (int k = 0; k < 64; k += 32) {
            bf16x8 af[4], bg[4];
            int ko = (((k >> 3) + quad) ^ sw) * 8;
#pragma unroll
            for (int mi = 0; mi < 4; ++mi)
                af[mi] = *(const bf16x8*)(As + (wm + mi * 16 + lm) * 64 + ko);
#pragma unroll
            for (int ni = 0; ni < 4; ++ni)
                bg[ni] = *(const bf16x8*)(Bs + (wn + ni * 16 + lm) * 64 + ko);
#pragma unroll
            for (int mi = 0; mi < 4; ++mi)
#pragma unroll
                for (int ni = 0; ni < 4; ++ni)
                    acc[mi][ni] = __builtin_amdgcn_mfma_f32_16x16x32_bf16(af[mi], bg[ni], acc[mi][ni], 0, 0, 0);
        }
        __syncthreads();
    }

    float w3v[4], b2v[4];
#pragma unroll
    for (int ni = 0; ni < 4; ++ni) {
        int col = n0 + wn + ni * 16 + lm;
        w3v[ni] = W3[col];
        b2v[ni] = b2[col];
    }
#pragma unroll
    for (int mi = 0; mi < 4; ++mi) {
#pragma unroll
        for (int r = 0; r < 4; ++r) {
            float s = 0.f;
#pragma unroll
            for (int ni = 0; ni < 4; ++ni)
                s += fmaxf(acc[mi][ni][r] + b2v[ni], 0.f) * w3v[ni];
            s += __shfl_xor(s, 1, 64);
            s += __shfl_xor(s, 2, 64);
            s += __shfl_xor(s, 4, 64);
            s += __shfl_xor(s, 8, 64);
            if (lm == 0)
                atomicAdd(out + row_base + m0 + wm + mi * 16 + quad * 4 + r, s);
        }
    }
}

// ---------------- launch ----------------

extern "C" void kernel_launch(void* const* d_in, const int* in_sizes, int n_in,
                              void* d_out, int out_size, void* d_ws, size_t ws_size,
                              hipStream_t stream) {
    const float* seq   = (const float*)d_in[0];
    const float* label = (const float*)d_in[1];
    const float* Wp    = (const float*)d_in[2];
    const float* Wl    = (const float*)d_in[3];
    const float* W1    = (const float*)d_in[4];
    const float* b1    = (const float*)d_in[5];
    const float* W2    = (const float*)d_in[6];
    const float* b2    = (const float*)d_in[7];
    const float* W3    = (const float*)d_in[8];
    const float* b3    = (const float*)d_in[9];
    float* out = (float*)d_out;
    (void)n_in; (void)in_sizes; (void)out_size;

    size_t off = 0;
    auto alloc = [&](size_t bytes) {
        void* p = (char*)d_ws + off;
        off += (bytes + 255) & ~(size_t)255;
        return p;
    };
    bf16* label_b = (bf16*)alloc((size_t)NLBL * 1024 * 2);
    bf16* WlT_b   = (bf16*)alloc((size_t)1024 * 1024 * 2);
    bf16* W1l_b   = (bf16*)alloc((size_t)1024 * 1024 * 2);
    bf16* W2_b    = (bf16*)alloc((size_t)1024 * 1024 * 2);
    bf16* M_bf    = (bf16*)alloc((size_t)1024 * 1024 * 2);
    float* hl     = (float*)alloc((size_t)NLBL * 1024 * 4);
    float* Pe     = (float*)alloc((size_t)B_SEQ * 1024 * 4);
    float* hpb    = (float*)alloc((size_t)B_SEQ * 1024 * 4);
    bf16* h1      = (bf16*)((char*)d_ws + off);

    size_t remain = (ws_size > off) ? (ws_size - off) : 0;
    long max_rows = (long)(remain / (1024 * 2));
    int chunk = (int)((max_rows / 128) * 128);
    if (chunk > NROWS) chunk = NROWS;
    if (chunk < 128) chunk = 128;

    // conversions
    {
        int n4 = (NLBL * 1024) / 4;
        convert_kernel<<<(n4 + 255) / 256, 256, 0, stream>>>(label, label_b, n4);
    }
    {
        int n4 = (1024 * 1024) / 4;
        convert_kernel<<<(n4 + 255) / 256, 256, 0, stream>>>(W2, W2_b, n4);
        convert_w1l<<<(n4 + 255) / 256, 256, 0, stream>>>(W1, W1l_b);
        transpose_convert<<<dim3(32, 32), 256, 0, stream>>>(Wl, WlT_b);
    }

    // protein path (f32 exact, coalesced wave-per-row)
    pe_kernel<<<256, 256, 0, stream>>>(seq, Wp, Pe);
    hpb_kernel<<<256, 256, 0, stream>>>(Pe, W1, b1, hpb);

    // label path: M = W1l @ Wl (64x64 tiles, 256 blocks), hl = label @ M.T
    gemm64_bt<<<dim3(16, 16), 256, 0, stream>>>(W1l_b, WlT_b, M_bf);
    gemm_bt_glds<0><<<dim3(8, (NLBL + 127) / 128), 256, 0, stream>>>(label_b, M_bf, (void*)hl, NLBL);

    init_out<<<(NROWS + 255) / 256, 256, 0, stream>>>(out, b3);

    if (chunk >= NROWS) {
        build_h1<<<NROWS / 2, 256, 0, stream>>>(hl, hpb, h1, 0);
        gemm_h2<1><<<NROWS / 128 * 8, 256, 0, stream>>>(h1, W2_b, b2, W3, out, 0);
    } else {
        for (int rb = 0; rb < NROWS; rb += chunk) {
            int rows = (NROWS - rb) < chunk ? (NROWS - rb) : chunk;
            build_h1<<<rows / 2, 256, 0, stream>>>(hl, hpb, h1, rb);
            gemm_h2<0><<<dim3(8, rows / 128), 256, 0, stream>>>(h1, W2_b, b2, W3, out, rb);
        }
    }
}

// Round 4
// 354.732 us; speedup vs baseline: 1.6059x; 1.1764x over previous
//
#include <hip/hip_runtime.h>
#include <hip/hip_bf16.h>
#include <stdint.h>

typedef __bf16 bf16;
typedef __bf16 bf16x4 __attribute__((ext_vector_type(4)));
typedef __bf16 bf16x8 __attribute__((ext_vector_type(8)));
typedef float floatx4 __attribute__((ext_vector_type(4)));

#define B_SEQ 16
#define NLBL  5000
#define DLAT  1024
#define PDIM  1100
#define NROWS (B_SEQ * NLBL)   // 80000 = 625 * 128

__device__ __forceinline__ void gload_lds16(const bf16* g, bf16* l) {
    __builtin_amdgcn_global_load_lds(
        (const __attribute__((address_space(1))) void*)g,
        (__attribute__((address_space(3))) void*)l, 16, 0, 0);
}

__device__ __forceinline__ bf16x8 cvt8(const float* s) {
    floatx4 a = *(const floatx4*)s;
    floatx4 b = *(const floatx4*)(s + 4);
    bf16x8 o;
    o[0] = (bf16)a.x; o[1] = (bf16)a.y; o[2] = (bf16)a.z; o[3] = (bf16)a.w;
    o[4] = (bf16)b.x; o[5] = (bf16)b.y; o[6] = (bf16)b.z; o[7] = (bf16)b.w;
    return o;
}

// ============ K1: prep — converts + Pe + out-init, horizontally fused ============
// block ranges: [0,2500) label cvt | [2500,3012) W2 cvt | [3012,3524) W1l cvt
//               [3524,4548) Wl transpose | [4548,4804) Pe | [4804,5117) out init
#define SEG1 2500
#define SEG2 3012
#define SEG3 3524
#define SEG4 4548
#define SEG5 4804
#define SEG6 5117

__global__ __launch_bounds__(256)
void prep_kernel(const float* __restrict__ label, bf16* __restrict__ label_b,
                 const float* __restrict__ W2, bf16* __restrict__ W2_b,
                 const float* __restrict__ W1, bf16* __restrict__ W1l_b,
                 const float* __restrict__ Wl, bf16* __restrict__ WlT_b,
                 const float* __restrict__ seq, const float* __restrict__ Wp,
                 float* __restrict__ Pe,
                 float* __restrict__ out, const float* __restrict__ b3) {
    __shared__ float tile[32][33];
    const int blk = blockIdx.x;
    const int t = threadIdx.x;

    if (blk < SEG1) {                       // label: 5000*1024/8 = 640000 threads exact
        int i = blk * 256 + t;
        ((bf16x8*)label_b)[i] = cvt8(label + (size_t)i * 8);
    } else if (blk < SEG2) {                // W2: 1024*1024/8 threads exact
        int i = (blk - SEG1) * 256 + t;
        ((bf16x8*)W2_b)[i] = cvt8(W2 + (size_t)i * 8);
    } else if (blk < SEG3) {                // W1[:,1024:2048] -> W1l_b
        int i = (blk - SEG2) * 256 + t;
        int o = i >> 7, c = (i & 127) * 8;
        ((bf16x8*)W1l_b)[i] = cvt8(W1 + (size_t)o * 2048 + 1024 + c);
    } else if (blk < SEG4) {                // WlT[l][d] = Wl[d][l]
        int local = blk - SEG3;
        int bx = (local & 31) * 32, by = (local >> 5) * 32;
        int tx = t & 31, ty = t >> 5;
#pragma unroll
        for (int i = 0; i < 32; i += 8)
            tile[ty + i][tx] = Wl[(size_t)(by + ty + i) * 1024 + bx + tx];
        __syncthreads();
#pragma unroll
        for (int i = 0; i < 32; i += 8)
            WlT_b[(size_t)(bx + ty + i) * 1024 + by + tx] = (bf16)tile[tx][ty + i];
    } else if (blk < SEG5) {                // Pe[b,d] = seq[b,:].Wp[d,:], wave per d
        int w = (blk - SEG4) * 4 + (t >> 6);
        int l = t & 63;
        floatx4 wv[5];
#pragma unroll
        for (int k = 0; k < 5; ++k) {
            int g = l + 64 * k;
            wv[k] = (g < 275) ? *(const floatx4*)(Wp + (size_t)w * PDIM + g * 4)
                              : floatx4{0.f, 0.f, 0.f, 0.f};
        }
        for (int b = 0; b < B_SEQ; ++b) {
            float acc = 0.f;
#pragma unroll
            for (int k = 0; k < 5; ++k) {
                int g = l + 64 * k;
                if (g < 275) {
                    floatx4 sv = *(const floatx4*)(seq + (size_t)b * PDIM + g * 4);
                    acc += wv[k].x * sv.x + wv[k].y * sv.y + wv[k].z * sv.z + wv[k].w * sv.w;
                }
            }
#pragma unroll
            for (int off = 32; off; off >>= 1) acc += __shfl_xor(acc, off, 64);
            if (l == 0) Pe[b * DLAT + w] = acc;
        }
    } else {                                // out init to b3
        int i = (blk - SEG5) * 256 + t;
        if (i < NROWS) out[i] = b3[0];
    }
}

// ============ K2: mid — hpb + M-product (W1l@Wl), horizontally fused ============
// blocks [0,256): hpb (wave per o) | [256,512): 64x64-tile GEMM M = W1l @ Wl

__global__ __launch_bounds__(256)
void mid_kernel(const float* __restrict__ Pe, const float* __restrict__ W1,
                const float* __restrict__ b1, float* __restrict__ hpb,
                const bf16* __restrict__ A, const bf16* __restrict__ Bt,
                bf16* __restrict__ C) {
    __shared__ bf16 As[64 * 64];
    __shared__ bf16 Bs[64 * 64];
    const int t = threadIdx.x;

    if (blockIdx.x < 256) {
        int w = blockIdx.x * 4 + (t >> 6);
        int l = t & 63;
        floatx4 wv[4];
#pragma unroll
        for (int k = 0; k < 4; ++k)
            wv[k] = *(const floatx4*)(W1 + (size_t)w * 2048 + (l + 64 * k) * 4);
        for (int b = 0; b < B_SEQ; ++b) {
            float acc = 0.f;
#pragma unroll
            for (int k = 0; k < 4; ++k) {
                floatx4 pv = *(const floatx4*)(Pe + (size_t)b * DLAT + (l + 64 * k) * 4);
                acc += wv[k].x * pv.x + wv[k].y * pv.y + wv[k].z * pv.z + wv[k].w * pv.w;
            }
#pragma unroll
            for (int off = 32; off; off >>= 1) acc += __shfl_xor(acc, off, 64);
            if (l == 0) hpb[b * DLAT + w] = acc + b1[w];
        }
        return;
    }

    int idx = blockIdx.x - 256;
    const int n0 = (idx & 15) * 64;
    const int m0 = (idx >> 4) * 64;
    const int wave = t >> 6, lane = t & 63;
    const int wm = (wave & 1) * 32, wn = (wave >> 1) * 32;
    const int lm = lane & 15, quad = lane >> 4;
    const int srow = t >> 2;
    const int sq = t & 3;

    floatx4 acc[2][2] = {};

    for (int k0 = 0; k0 < 1024; k0 += 64) {
#pragma unroll
        for (int p = 0; p < 2; ++p) {
            int cg = (p * 4 + sq) ^ (srow & 7);
            gload_lds16(A + (size_t)(m0 + srow) * 1024 + k0 + cg * 8, As + p * 2048 + (t & 192) * 8);
            gload_lds16(Bt + (size_t)(n0 + srow) * 1024 + k0 + cg * 8, Bs + p * 2048 + (t & 192) * 8);
        }
        __syncthreads();
#pragma unroll
        for (int ks = 0; ks < 2; ++ks) {
            bf16x8 af[2], bg[2];
#pragma unroll
            for (int mi = 0; mi < 2; ++mi) {
                int r = wm + mi * 16 + lm;
                int cg = (ks * 4 + quad) ^ (r & 7);
                af[mi] = *(const bf16x8*)(As + (cg >> 2) * 2048 + r * 32 + (cg & 3) * 8);
            }
#pragma unroll
            for (int ni = 0; ni < 2; ++ni) {
                int r = wn + ni * 16 + lm;
                int cg = (ks * 4 + quad) ^ (r & 7);
                bg[ni] = *(const bf16x8*)(Bs + (cg >> 2) * 2048 + r * 32 + (cg & 3) * 8);
            }
#pragma unroll
            for (int mi = 0; mi < 2; ++mi)
#pragma unroll
                for (int ni = 0; ni < 2; ++ni)
                    acc[mi][ni] = __builtin_amdgcn_mfma_f32_16x16x32_bf16(af[mi], bg[ni], acc[mi][ni], 0, 0, 0);
        }
        __syncthreads();
    }

#pragma unroll
    for (int mi = 0; mi < 2; ++mi)
#pragma unroll
        for (int r = 0; r < 4; ++r)
#pragma unroll
            for (int ni = 0; ni < 2; ++ni) {
                int row = m0 + wm + mi * 16 + quad * 4 + r;
                int col = n0 + wn + ni * 16 + lm;
                C[(size_t)row * 1024 + col] = (bf16)acc[mi][ni][r];
            }
}

// ============ K3: hl GEMM (label @ M.T) with fused h1 build-epilogue ============
// h1[(b*5000+n), d] = bf16(relu(hpb[b,d] + hl[n,d])) for all 16 b.

__global__ __launch_bounds__(256)
void hl_h1_kernel(const bf16* __restrict__ A, const bf16* __restrict__ Bt,
                  const float* __restrict__ hpb, bf16* __restrict__ h1) {
    __shared__ bf16 As[128 * 64];
    __shared__ bf16 Bs[128 * 64];
    const int t = threadIdx.x;
    const int n0 = blockIdx.x * 128;    // d-tile (8)
    const int m0 = blockIdx.y * 128;    // n-tile (40, last partial)
    const int wave = t >> 6, lane = t & 63;
    const int wm = (wave & 1) * 64, wn = (wave >> 1) * 64;
    const int lm = lane & 15, quad = lane >> 4;
    const int sw = lm & 7;
    const int srow = t >> 3;
    const int scg0 = t & 7;
    const int sbase = (t & 192) * 8;

    floatx4 acc[4][4] = {};

    for (int k0 = 0; k0 < 1024; k0 += 64) {
#pragma unroll
        for (int p = 0; p < 4; ++p) {
            int row = p * 32 + srow;
            int cg = scg0 ^ (row & 7);
            int grow = m0 + row; if (grow >= NLBL) grow = NLBL - 1;
            gload_lds16(A + (size_t)grow * 1024 + k0 + cg * 8, As + p * 2048 + sbase);
        }
#pragma unroll
        for (int p = 0; p < 4; ++p) {
            int row = p * 32 + srow;
            int cg = scg0 ^ (row & 7);
            gload_lds16(Bt + (size_t)(n0 + row) * 1024 + k0 + cg * 8, Bs + p * 2048 + sbase);
        }
        __syncthreads();
#pragma unroll
        for (int k = 0; k < 64; k += 32) {
            bf16x8 af[4], bg[4];
            int ko = (((k >> 3) + quad) ^ sw) * 8;
#pragma unroll
            for (int mi = 0; mi < 4; ++mi)
                af[mi] = *(const bf16x8*)(As + (wm + mi * 16 + lm) * 64 + ko);
#pragma unroll
            for (int ni = 0; ni < 4; ++ni)
                bg[ni] = *(const bf16x8*)(Bs + (wn + ni * 16 + lm) * 64 + ko);
#pragma unroll
            for (int mi = 0; mi < 4; ++mi)
#pragma unroll
                for (int ni = 0; ni < 4; ++ni)
                    acc[mi][ni] = __builtin_amdgcn_mfma_f32_16x16x32_bf16(af[mi], bg[ni], acc[mi][ni], 0, 0, 0);
        }
        __syncthreads();
    }

    // stage hpb[0:16, n0:n0+128] into LDS (overlaying As — all reads done)
    float* hpbs = (float*)As;           // 16*128*4 = 8 KB <= 16 KB
    {
        int dl = (t & 31) * 4;
        int b = t >> 5;                 // 0..7
        *(floatx4*)(hpbs + b * 128 + dl) =
            *(const floatx4*)(hpb + (size_t)b * DLAT + n0 + dl);
        *(floatx4*)(hpbs + (b + 8) * 128 + dl) =
            *(const floatx4*)(hpb + (size_t)(b + 8) * DLAT + n0 + dl);
    }
    __syncthreads();

#pragma unroll
    for (int mi = 0; mi < 4; ++mi) {
#pragma unroll
        for (int r = 0; r < 4; ++r) {
            int n = m0 + wm + mi * 16 + quad * 4 + r;
            if (n >= NLBL) continue;
#pragma unroll
            for (int ni = 0; ni < 4; ++ni) {
                int dl = wn + ni * 16 + lm;
                float hlv = acc[mi][ni][r];
                bf16* dst = h1 + (size_t)n * 1024 + n0 + dl;
#pragma unroll
                for (int b = 0; b < B_SEQ; ++b) {
                    float v = fmaxf(hpbs[b * 128 + dl] + hlv, 0.f);
                    dst[(size_t)b * NLBL * 1024] = (bf16)v;
                    // note: dst advances by b implicitly via index above
                    dst += 0; // keep pointer; offset applied in index
                }
            }
        }
    }
}

// ============ K4: main GEMM h1 @ W2.T + fused relu/b2/W3 epilogue ============
// flat grid 5000, XCD-affinity: block->XCD = id%8, each XCD owns 78 contiguous
// m-tiles with n fastest -> A-tile lives in ONE XCD's L2.

__global__ __launch_bounds__(256)
void gemm_h2(const bf16* __restrict__ h1, const bf16* __restrict__ W2b,
             const float* __restrict__ b2, const float* __restrict__ W3,
             float* __restrict__ out) {
    __shared__ bf16 As[128 * 64];
    __shared__ bf16 Bs[128 * 64];
    const int t = threadIdx.x;
    int flat = blockIdx.x;
    int x = flat & 7;
    int s = flat >> 3;
    int mt, nt;
    if (s < 624) { mt = x * 78 + (s >> 3); nt = s & 7; }
    else         { mt = 624; nt = x; }
    const int m0 = mt * 128, n0 = nt * 128;

    const int wave = t >> 6, lane = t & 63;
    const int wm = (wave & 1) * 64, wn = (wave >> 1) * 64;
    const int lm = lane & 15, quad = lane >> 4;
    const int sw = lm & 7;
    const int srow = t >> 3;
    const int scg0 = t & 7;
    const int sbase = (t & 192) * 8;

    floatx4 acc[4][4] = {};
    const bf16* Abase = h1 + (size_t)m0 * 1024;
    const bf16* Bbase = W2b + (size_t)n0 * 1024;

    for (int k0 = 0; k0 < 1024; k0 += 64) {
#pragma unroll
        for (int p = 0; p < 4; ++p) {
            int row = p * 32 + srow;
            int cg = scg0 ^ (row & 7);
            gload_lds16(Abase + (size_t)row * 1024 + k0 + cg * 8, As + p * 2048 + sbase);
        }
#pragma unroll
        for (int p = 0; p < 4; ++p) {
            int row = p * 32 + srow;
            int cg = scg0 ^ (row & 7);
            gload_lds16(Bbase + (size_t)row * 1024 + k0 + cg * 8, Bs + p * 2048 + sbase);
        }
        __syncthreads();
#pragma unroll
        for (int k = 0; k < 64; k += 32) {
            bf16x8 af[4], bg[4];
            int ko = (((k >> 3) + quad) ^ sw) * 8;
#pragma unroll
            for (int mi = 0; mi < 4; ++mi)
                af[mi] = *(const bf16x8*)(As + (wm + mi * 16 + lm) * 64 + ko);
#pragma unroll
            for (int ni = 0; ni < 4; ++ni)
                bg[ni] = *(const bf16x8*)(Bs + (wn + ni * 16 + lm) * 64 + ko);
#pragma unroll
            for (int mi = 0; mi < 4; ++mi)
#pragma unroll
                for (int ni = 0; ni < 4; ++ni)
                    acc[mi][ni] = __builtin_amdgcn_mfma_f32_16x16x32_bf16(af[mi], bg[ni], acc[mi][ni], 0, 0, 0);
        }
        __syncthreads();
    }

    float w3v[4], b2v[4];
#pragma unroll
    for (int ni = 0; ni < 4; ++ni) {
        int col = n0 + wn + ni * 16 + lm;
        w3v[ni] = W3[col];
        b2v[ni] = b2[col];
    }
#pragma unroll
    for (int mi = 0; mi < 4; ++mi) {
#pragma unroll
        for (int r = 0; r < 4; ++r) {
            float sacc = 0.f;
#pragma unroll
            for (int ni = 0; ni < 4; ++ni)
                sacc += fmaxf(acc[mi][ni][r] + b2v[ni], 0.f) * w3v[ni];
            sacc += __shfl_xor(sacc, 1, 64);
            sacc += __shfl_xor(sacc, 2, 64);
            sacc += __shfl_xor(sacc, 4, 64);
            sacc += __shfl_xor(sacc, 8, 64);
            if (lm == 0)
                atomicAdd(out + m0 + wm + mi * 16 + quad * 4 + r, sacc);
        }
    }
}

// ---------------- launch ----------------

extern "C" void kernel_launch(void* const* d_in, const int* in_sizes, int n_in,
                              void* d_out, int out_size, void* d_ws, size_t ws_size,
                              hipStream_t stream) {
    const float* seq   = (const float*)d_in[0];
    const float* label = (const float*)d_in[1];
    const float* Wp    = (const float*)d_in[2];
    const float* Wl    = (const float*)d_in[3];
    const float* W1    = (const float*)d_in[4];
    const float* b1    = (const float*)d_in[5];
    const float* W2    = (const float*)d_in[6];
    const float* b2    = (const float*)d_in[7];
    const float* W3    = (const float*)d_in[8];
    const float* b3    = (const float*)d_in[9];
    float* out = (float*)d_out;
    (void)n_in; (void)in_sizes; (void)out_size; (void)ws_size;

    size_t off = 0;
    auto alloc = [&](size_t bytes) {
        void* p = (char*)d_ws + off;
        off += (bytes + 255) & ~(size_t)255;
        return p;
    };
    bf16* label_b = (bf16*)alloc((size_t)NLBL * 1024 * 2);
    bf16* WlT_b   = (bf16*)alloc((size_t)1024 * 1024 * 2);
    bf16* W1l_b   = (bf16*)alloc((size_t)1024 * 1024 * 2);
    bf16* W2_b    = (bf16*)alloc((size_t)1024 * 1024 * 2);
    bf16* M_bf    = (bf16*)alloc((size_t)1024 * 1024 * 2);
    float* Pe     = (float*)alloc((size_t)B_SEQ * 1024 * 4);
    float* hpb    = (float*)alloc((size_t)B_SEQ * 1024 * 4);
    bf16* h1      = (bf16*)alloc((size_t)NROWS * 1024 * 2);

    prep_kernel<<<SEG6, 256, 0, stream>>>(label, label_b, W2, W2_b, W1, W1l_b,
                                          Wl, WlT_b, seq, Wp, Pe, out, b3);
    mid_kernel<<<512, 256, 0, stream>>>(Pe, W1, b1, hpb, W1l_b, WlT_b, M_bf);
    hl_h1_kernel<<<dim3(8, 40), 256, 0, stream>>>(label_b, M_bf, hpb, h1);
    gemm_h2<<<5000, 256, 0, stream>>>(h1, W2_b, b2, W3, out);
}

// Round 5
// 349.783 us; speedup vs baseline: 1.6287x; 1.0141x over previous
//
#include <hip/hip_runtime.h>
#include <hip/hip_bf16.h>
#include <stdint.h>

typedef __bf16 bf16;
typedef __bf16 bf16x4 __attribute__((ext_vector_type(4)));
typedef __bf16 bf16x8 __attribute__((ext_vector_type(8)));
typedef float floatx4 __attribute__((ext_vector_type(4)));

#define B_SEQ 16
#define NLBL  5000
#define DLAT  1024
#define PDIM  1100
#define NROWS (B_SEQ * NLBL)   // 80000 = 625 * 128

__device__ __forceinline__ void gload_lds16(const bf16* g, bf16* l) {
    __builtin_amdgcn_global_load_lds(
        (const __attribute__((address_space(1))) void*)g,
        (__attribute__((address_space(3))) void*)l, 16, 0, 0);
}

__device__ __forceinline__ bf16x8 cvt8(const float* s) {
    floatx4 a = *(const floatx4*)s;
    floatx4 b = *(const floatx4*)(s + 4);
    bf16x8 o;
    o[0] = (bf16)a.x; o[1] = (bf16)a.y; o[2] = (bf16)a.z; o[3] = (bf16)a.w;
    o[4] = (bf16)b.x; o[5] = (bf16)b.y; o[6] = (bf16)b.z; o[7] = (bf16)b.w;
    return o;
}

// ============ K1: prep ============
// [0,256)       M-GEMM: M[d,l] = sum_k W1[d,1024+k]*Wl[k,l]  (inline f32->bf16)
// [256,2756)    label f32->bf16
// [2756,3268)   W2 f32->bf16
// [3268,3524)   Pe[b,d] = seq[b,:].Wp[d,:]  (f32 exact)
// [3524,3837)   out init to b3
#define PSEG_M    256
#define PSEG_LAB  2756
#define PSEG_W2   3268
#define PSEG_PE   3524
#define PSEG_END  3837

__global__ __launch_bounds__(256)
void prep_kernel(const float* __restrict__ label, bf16* __restrict__ label_b,
                 const float* __restrict__ W2, bf16* __restrict__ W2_b,
                 const float* __restrict__ W1, const float* __restrict__ Wl,
                 bf16* __restrict__ M_bf,
                 const float* __restrict__ seq, const float* __restrict__ Wp,
                 float* __restrict__ Pe,
                 float* __restrict__ out, const float* __restrict__ b3) {
    __shared__ bf16 MAs[64 * 72];
    __shared__ bf16 MBs[64 * 72];
    const int blk = blockIdx.x;
    const int t = threadIdx.x;

    if (blk < PSEG_M) {                     // M-product, 64x64 tiles, 16x16 grid
        const int m0 = (blk >> 4) * 64;     // d rows
        const int n0g = (blk & 15) * 64;    // l cols
        const int wave = t >> 6, lane = t & 63;
        const int wm = (wave & 1) * 32, wn = (wave >> 1) * 32;
        const int lm = lane & 15, quad = lane >> 4;
        const int a_r = t >> 2, a_c = (t & 3) * 16;
        const int b_kr = t >> 4, b_l = (t & 15) * 4;
        floatx4 acc[2][2] = {};

        for (int k0 = 0; k0 < 1024; k0 += 64) {
            const float* ap = W1 + (size_t)(m0 + a_r) * 2048 + 1024 + k0 + a_c;
            *(bf16x8*)(MAs + a_r * 72 + a_c) = cvt8(ap);
            *(bf16x8*)(MAs + a_r * 72 + a_c + 8) = cvt8(ap + 8);
#pragma unroll
            for (int ps = 0; ps < 4; ++ps) {
                int kr = b_kr + ps * 16;
                floatx4 v = *(const floatx4*)(Wl + (size_t)(k0 + kr) * 1024 + n0g + b_l);
                MBs[(b_l + 0) * 72 + kr] = (bf16)v.x;
                MBs[(b_l + 1) * 72 + kr] = (bf16)v.y;
                MBs[(b_l + 2) * 72 + kr] = (bf16)v.z;
                MBs[(b_l + 3) * 72 + kr] = (bf16)v.w;
            }
            __syncthreads();
#pragma unroll
            for (int ks = 0; ks < 2; ++ks) {
                bf16x8 af[2], bg[2];
#pragma unroll
                for (int mi = 0; mi < 2; ++mi)
                    af[mi] = *(const bf16x8*)(MAs + (wm + mi * 16 + lm) * 72 + ks * 32 + quad * 8);
#pragma unroll
                for (int ni = 0; ni < 2; ++ni)
                    bg[ni] = *(const bf16x8*)(MBs + (wn + ni * 16 + lm) * 72 + ks * 32 + quad * 8);
#pragma unroll
                for (int mi = 0; mi < 2; ++mi)
#pragma unroll
                    for (int ni = 0; ni < 2; ++ni)
                        acc[mi][ni] = __builtin_amdgcn_mfma_f32_16x16x32_bf16(af[mi], bg[ni], acc[mi][ni], 0, 0, 0);
            }
            __syncthreads();
        }
#pragma unroll
        for (int mi = 0; mi < 2; ++mi)
#pragma unroll
            for (int r = 0; r < 4; ++r)
#pragma unroll
                for (int ni = 0; ni < 2; ++ni)
                    M_bf[(size_t)(m0 + wm + mi * 16 + quad * 4 + r) * 1024 + n0g + wn + ni * 16 + lm] =
                        (bf16)acc[mi][ni][r];
    } else if (blk < PSEG_LAB) {            // label convert: 2500*256 granules exact
        int i = (blk - PSEG_M) * 256 + t;
        ((bf16x8*)label_b)[i] = cvt8(label + (size_t)i * 8);
    } else if (blk < PSEG_W2) {             // W2 convert
        int i = (blk - PSEG_LAB) * 256 + t;
        ((bf16x8*)W2_b)[i] = cvt8(W2 + (size_t)i * 8);
    } else if (blk < PSEG_PE) {             // Pe, wave per d
        int w = (blk - PSEG_W2) * 4 + (t >> 6);
        int l = t & 63;
        floatx4 wv[5];
#pragma unroll
        for (int k = 0; k < 5; ++k) {
            int g = l + 64 * k;
            wv[k] = (g < 275) ? *(const floatx4*)(Wp + (size_t)w * PDIM + g * 4)
                              : floatx4{0.f, 0.f, 0.f, 0.f};
        }
        for (int b = 0; b < B_SEQ; ++b) {
            float acc = 0.f;
#pragma unroll
            for (int k = 0; k < 5; ++k) {
                int g = l + 64 * k;
                if (g < 275) {
                    floatx4 sv = *(const floatx4*)(seq + (size_t)b * PDIM + g * 4);
                    acc += wv[k].x * sv.x + wv[k].y * sv.y + wv[k].z * sv.z + wv[k].w * sv.w;
                }
            }
#pragma unroll
            for (int off = 32; off; off >>= 1) acc += __shfl_xor(acc, off, 64);
            if (l == 0) Pe[b * DLAT + w] = acc;
        }
    } else {                                // out init
        int i = (blk - PSEG_PE) * 256 + t;
        if (i < NROWS) out[i] = b3[0];
    }
}

// ============ K2: hpb[b,o] = b1[o] + Pe[b,:].W1[o,0:1024]  (f32 exact) ============

__global__ __launch_bounds__(256)
void hpb_kernel(const float* __restrict__ Pe, const float* __restrict__ W1,
                const float* __restrict__ b1, float* __restrict__ hpb) {
    int w = blockIdx.x * 4 + (threadIdx.x >> 6);
    int l = threadIdx.x & 63;
    floatx4 wv[4];
#pragma unroll
    for (int k = 0; k < 4; ++k)
        wv[k] = *(const floatx4*)(W1 + (size_t)w * 2048 + (l + 64 * k) * 4);
    for (int b = 0; b < B_SEQ; ++b) {
        float acc = 0.f;
#pragma unroll
        for (int k = 0; k < 4; ++k) {
            floatx4 pv = *(const floatx4*)(Pe + (size_t)b * DLAT + (l + 64 * k) * 4);
            acc += wv[k].x * pv.x + wv[k].y * pv.y + wv[k].z * pv.z + wv[k].w * pv.w;
        }
#pragma unroll
        for (int off = 32; off; off >>= 1) acc += __shfl_xor(acc, off, 64);
        if (l == 0) hpb[b * DLAT + w] = acc + b1[w];
    }
}

// ============ K3: hl GEMM (label @ M.T) with coalesced h1 epilogue ============
// h1[(b*5000+n), d] = bf16(relu(hpb[b,d] + hl[n,d])) for all 16 b.
// Epilogue: acc -> LDS (bf16, stride 136) -> row-contiguous bf16x8 stores.

__global__ __launch_bounds__(256)
void hl_h1_kernel(const bf16* __restrict__ A, const bf16* __restrict__ Bt,
                  const float* __restrict__ hpb, bf16* __restrict__ h1) {
    __shared__ __align__(16) char smem[43008];
    bf16* As = (bf16*)smem;                 // 16 KB (K-loop)
    bf16* Bs = (bf16*)(smem + 16384);       // 16 KB (K-loop)
    bf16* Ls = (bf16*)smem;                 // 128*136*2 = 34816 B (epilogue)
    float* hpbs = (float*)(smem + 34816);   // 16*128*4 = 8192 B (epilogue)

    const int t = threadIdx.x;
    const int n0 = blockIdx.x * 128;        // d-tile (8)
    const int m0 = blockIdx.y * 128;        // n-tile (40, last partial)
    const int wave = t >> 6, lane = t & 63;
    const int wm = (wave & 1) * 64, wn = (wave >> 1) * 64;
    const int lm = lane & 15, quad = lane >> 4;
    const int sw = lm & 7;
    const int srow = t >> 3;
    const int scg0 = t & 7;
    const int sbase = (t & 192) * 8;

    floatx4 acc[4][4] = {};

    for (int k0 = 0; k0 < 1024; k0 += 64) {
#pragma unroll
        for (int p = 0; p < 4; ++p) {
            int row = p * 32 + srow;
            int cg = scg0 ^ (row & 7);
            int grow = m0 + row; if (grow >= NLBL) grow = NLBL - 1;
            gload_lds16(A + (size_t)grow * 1024 + k0 + cg * 8, As + p * 2048 + sbase);
        }
#pragma unroll
        for (int p = 0; p < 4; ++p) {
            int row = p * 32 + srow;
            int cg = scg0 ^ (row & 7);
            gload_lds16(Bt + (size_t)(n0 + row) * 1024 + k0 + cg * 8, Bs + p * 2048 + sbase);
        }
        __syncthreads();
#pragma unroll
        for (int k = 0; k < 64; k += 32) {
            bf16x8 af[4], bg[4];
            int ko = (((k >> 3) + quad) ^ sw) * 8;
#pragma unroll
            for (int mi = 0; mi < 4; ++mi)
                af[mi] = *(const bf16x8*)(As + (wm + mi * 16 + lm) * 64 + ko);
#pragma unroll
            for (int ni = 0; ni < 4; ++ni)
                bg[ni] = *(const bf16x8*)(Bs + (wn + ni * 16 + lm) * 64 + ko);
#pragma unroll
            for (int mi = 0; mi < 4; ++mi)
#pragma unroll
                for (int ni = 0; ni < 4; ++ni)
                    acc[mi][ni] = __builtin_amdgcn_mfma_f32_16x16x32_bf16(af[mi], bg[ni], acc[mi][ni], 0, 0, 0);
        }
        __syncthreads();
    }

    // acc -> Ls (bf16 hl tile), and stage hpb slice
#pragma unroll
    for (int mi = 0; mi < 4; ++mi)
#pragma unroll
        for (int r = 0; r < 4; ++r)
#pragma unroll
            for (int ni = 0; ni < 4; ++ni)
                Ls[(wm + mi * 16 + quad * 4 + r) * 136 + wn + ni * 16 + lm] =
                    (bf16)acc[mi][ni][r];
    {
        int dl = (t & 31) * 4;
        int b = t >> 5;                     // 0..7
        *(floatx4*)(hpbs + b * 128 + dl) =
            *(const floatx4*)(hpb + (size_t)b * DLAT + n0 + dl);
        *(floatx4*)(hpbs + (b + 8) * 128 + dl) =
            *(const floatx4*)(hpb + (size_t)(b + 8) * DLAT + n0 + dl);
    }
    __syncthreads();

    // read hl row-contiguous once, then 16 b passes of add+relu+bf16x8 stores
    const int g = t & 15;                   // d-granule (16B)
    const int r0 = t >> 4;                  // 0..15 base row
    bf16x8 hlv[8];
#pragma unroll
    for (int p = 0; p < 8; ++p)
        hlv[p] = *(const bf16x8*)(Ls + (p * 16 + r0) * 136 + g * 8);

    for (int b = 0; b < B_SEQ; ++b) {
        floatx4 h0 = *(const floatx4*)(hpbs + b * 128 + g * 8);
        floatx4 h4 = *(const floatx4*)(hpbs + b * 128 + g * 8 + 4);
        size_t rowbase = (size_t)b * NLBL * 1024;
#pragma unroll
        for (int p = 0; p < 8; ++p) {
            int n = m0 + p * 16 + r0;
            if (n >= NLBL) continue;
            bf16x8 o;
            o[0] = (bf16)fmaxf((float)hlv[p][0] + h0.x, 0.f);
            o[1] = (bf16)fmaxf((float)hlv[p][1] + h0.y, 0.f);
            o[2] = (bf16)fmaxf((float)hlv[p][2] + h0.z, 0.f);
            o[3] = (bf16)fmaxf((float)hlv[p][3] + h0.w, 0.f);
            o[4] = (bf16)fmaxf((float)hlv[p][4] + h4.x, 0.f);
            o[5] = (bf16)fmaxf((float)hlv[p][5] + h4.y, 0.f);
            o[6] = (bf16)fmaxf((float)hlv[p][6] + h4.z, 0.f);
            o[7] = (bf16)fmaxf((float)hlv[p][7] + h4.w, 0.f);
            *(bf16x8*)(h1 + rowbase + (size_t)n * 1024 + n0 + g * 8) = o;
        }
    }
}

// ============ K4: main GEMM h1 @ W2.T + fused relu/b2/W3 epilogue ============
// flat grid 5000, XCD-affinity: block->XCD = id%8, each XCD owns 78 contiguous
// m-tiles with n fastest -> an h1 tile is fetched into ONE XCD's L2.

__global__ __launch_bounds__(256)
void gemm_h2(const bf16* __restrict__ h1, const bf16* __restrict__ W2b,
             const float* __restrict__ b2, const float* __restrict__ W3,
             float* __restrict__ out) {
    __shared__ bf16 As[128 * 64];
    __shared__ bf16 Bs[128 * 64];
    const int t = threadIdx.x;
    int flat = blockIdx.x;
    int x = flat & 7;
    int s = flat >> 3;
    int mt, nt;
    if (s < 624) { mt = x * 78 + (s >> 3); nt = s & 7; }
    else         { mt = 624; nt = x; }
    const int m0 = mt * 128, n0 = nt * 128;

    const int wave = t >> 6, lane = t & 63;
    const int wm = (wave & 1) * 64, wn = (wave >> 1) * 64;
    const int lm = lane & 15, quad = lane >> 4;
    const int sw = lm & 7;
    const int srow = t >> 3;
    const int scg0 = t & 7;
    const int sbase = (t & 192) * 8;

    floatx4 acc[4][4] = {};
    const bf16* Abase = h1 + (size_t)m0 * 1024;
    const bf16* Bbase = W2b + (size_t)n0 * 1024;

    for (int k0 = 0; k0 < 1024; k0 += 64) {
#pragma unroll
        for (int p = 0; p < 4; ++p) {
            int row = p * 32 + srow;
            int cg = scg0 ^ (row & 7);
            gload_lds16(Abase + (size_t)row * 1024 + k0 + cg * 8, As + p * 2048 + sbase);
        }
#pragma unroll
        for (int p = 0; p < 4; ++p) {
            int row = p * 32 + srow;
            int cg = scg0 ^ (row & 7);
            gload_lds16(Bbase + (size_t)row * 1024 + k0 + cg * 8, Bs + p * 2048 + sbase);
        }
        __syncthreads();
#pragma unroll
        for (int k = 0; k < 64; k += 32) {
            bf16x8 af[4], bg[4];
            int ko = (((k >> 3) + quad) ^ sw) * 8;
#pragma unroll
            for (int mi = 0; mi < 4; ++mi)
                af[mi] = *(const bf16x8*)(As + (wm + mi * 16 + lm) * 64 + ko);
#pragma unroll
            for (int ni = 0; ni < 4; ++ni)
                bg[ni] = *(const bf16x8*)(Bs + (wn + ni * 16 + lm) * 64 + ko);
#pragma unroll
            for (int mi = 0; mi < 4; ++mi)
#pragma unroll
                for (int ni = 0; ni < 4; ++ni)
                    acc[mi][ni] = __builtin_amdgcn_mfma_f32_16x16x32_bf16(af[mi], bg[ni], acc[mi][ni], 0, 0, 0);
        }
        __syncthreads();
    }

    float w3v[4], b2v[4];
#pragma unroll
    for (int ni = 0; ni < 4; ++ni) {
        int col = n0 + wn + ni * 16 + lm;
        w3v[ni] = W3[col];
        b2v[ni] = b2[col];
    }
#pragma unroll
    for (int mi = 0; mi < 4; ++mi) {
#pragma unroll
        for (int r = 0; r < 4; ++r) {
            float sacc = 0.f;
#pragma unroll
            for (int ni = 0; ni < 4; ++ni)
                sacc += fmaxf(acc[mi][ni][r] + b2v[ni], 0.f) * w3v[ni];
            sacc += __shfl_xor(sacc, 1, 64);
            sacc += __shfl_xor(sacc, 2, 64);
            sacc += __shfl_xor(sacc, 4, 64);
            sacc += __shfl_xor(sacc, 8, 64);
            if (lm == 0)
                atomicAdd(out + m0 + wm + mi * 16 + quad * 4 + r, sacc);
        }
    }
}

// ---------------- launch ----------------

extern "C" void kernel_launch(void* const* d_in, const int* in_sizes, int n_in,
                              void* d_out, int out_size, void* d_ws, size_t ws_size,
                              hipStream_t stream) {
    const float* seq   = (const float*)d_in[0];
    const float* label = (const float*)d_in[1];
    const float* Wp    = (const float*)d_in[2];
    const float* Wl    = (const float*)d_in[3];
    const float* W1    = (const float*)d_in[4];
    const float* b1    = (const float*)d_in[5];
    const float* W2    = (const float*)d_in[6];
    const float* b2    = (const float*)d_in[7];
    const float* W3    = (const float*)d_in[8];
    const float* b3    = (const float*)d_in[9];
    float* out = (float*)d_out;
    (void)n_in; (void)in_sizes; (void)out_size; (void)ws_size;

    size_t off = 0;
    auto alloc = [&](size_t bytes) {
        void* p = (char*)d_ws + off;
        off += (bytes + 255) & ~(size_t)255;
        return p;
    };
    bf16* label_b = (bf16*)alloc((size_t)NLBL * 1024 * 2);
    bf16* W2_b    = (bf16*)alloc((size_t)1024 * 1024 * 2);
    bf16* M_bf    = (bf16*)alloc((size_t)1024 * 1024 * 2);
    float* Pe     = (float*)alloc((size_t)B_SEQ * 1024 * 4);
    float* hpb    = (float*)alloc((size_t)B_SEQ * 1024 * 4);
    bf16* h1      = (bf16*)alloc((size_t)NROWS * 1024 * 2);

    prep_kernel<<<PSEG_END, 256, 0, stream>>>(label, label_b, W2, W2_b, W1, Wl,
                                              M_bf, seq, Wp, Pe, out, b3);
    hpb_kernel<<<256, 256, 0, stream>>>(Pe, W1, b1, hpb);
    hl_h1_kernel<<<dim3(8, 40), 256, 0, stream>>>(label_b, M_bf, hpb, h1);
    gemm_h2<<<5000, 256, 0, stream>>>(h1, W2_b, b2, W3, out);
}